// Round 10
// baseline (184.477 us; speedup 1.0000x reference)
//
#include <hip/hip_runtime.h>

#define NF   20000
#define NALL 60000
#define NE   640000
#define DD   128
#define AA   64

typedef __attribute__((ext_vector_type(8))) short short8;
typedef __attribute__((ext_vector_type(4))) float f32x4;

__device__ __forceinline__ unsigned short f2b(float x) {
    unsigned int u = __float_as_uint(x);
    return (unsigned short)((u + 0x7FFFu + ((u >> 16) & 1u)) >> 16);  // RNE
}
__device__ __forceinline__ float b2f(unsigned short v) {
    return __uint_as_float(((unsigned int)v) << 16);
}
__device__ __forceinline__ short8 pack8(float4 a, float4 b) {
    short8 r;
    r[0]=(short)f2b(a.x); r[1]=(short)f2b(a.y); r[2]=(short)f2b(a.z); r[3]=(short)f2b(a.w);
    r[4]=(short)f2b(b.x); r[5]=(short)f2b(b.y); r[6]=(short)f2b(b.z); r[7]=(short)f2b(b.w);
    return r;
}

// ---- K1: fused conv+proj. Loads fp32 embs, converts (writes embB bf16),
// computes P1 = feat@W1+bias, P2 = [feat;hid]@W2 (bf16) via MFMA. W from fp32 on the fly.
__global__ __launch_bounds__(256) void embproj_kernel(
    const float* __restrict__ featEmb, const float* __restrict__ hidEmb,
    const float* __restrict__ wK, const float* __restrict__ bias,
    unsigned short* __restrict__ embB,
    unsigned short* __restrict__ P1b, unsigned short* __restrict__ P2b)
{
    const int wave = threadIdx.x >> 6, lane = threadIdx.x & 63;
    const int rt = blockIdx.x * 4 + wave;
    if (rt >= NALL / 16) return;
    const int row0 = rt * 16;
    const int m = lane & 15, quad = lane >> 4;

    const int row = row0 + m;   // NF % 16 == 0: no tile straddles the feat/hid boundary
    const float* src = (row < NF) ? featEmb + (size_t)row * DD
                                  : hidEmb + (size_t)(row - NF) * DD;
    short8 afr[4];
    #pragma unroll
    for (int kc = 0; kc < 4; ++kc) {
        float4 a0 = *(const float4*)&src[kc * 32 + quad * 8];
        float4 a1 = *(const float4*)&src[kc * 32 + quad * 8 + 4];
        afr[kc] = pack8(a0, a1);
        *(short8*)&embB[(size_t)row * DD + kc * 32 + quad * 8] = afr[kc];
    }

    const float* W2 = wK + DD * AA;   // rows 128..255 of w_kernel
    #pragma unroll
    for (int nt = 0; nt < 4; ++nt) {
        f32x4 acc = {0.f, 0.f, 0.f, 0.f};
        #pragma unroll
        for (int kc = 0; kc < 4; ++kc) {
            short8 bfr;
            #pragma unroll
            for (int j = 0; j < 8; ++j)
                bfr[j] = (short)f2b(W2[(kc * 32 + quad * 8 + j) * AA + nt * 16 + m]);
            acc = __builtin_amdgcn_mfma_f32_16x16x32_bf16(afr[kc], bfr, acc, 0, 0, 0);
        }
        #pragma unroll
        for (int r = 0; r < 4; ++r)   // C/D: col=lane&15, row=quad*4+r
            P2b[(size_t)(row0 + quad * 4 + r) * AA + nt * 16 + m] = f2b(acc[r]);
    }
    if (row0 < NF) {
        #pragma unroll
        for (int nt = 0; nt < 4; ++nt) {
            f32x4 acc = {0.f, 0.f, 0.f, 0.f};
            #pragma unroll
            for (int kc = 0; kc < 4; ++kc) {
                short8 bfr;
                #pragma unroll
                for (int j = 0; j < 8; ++j)
                    bfr[j] = (short)f2b(wK[(kc * 32 + quad * 8 + j) * AA + nt * 16 + m]);
                acc = __builtin_amdgcn_mfma_f32_16x16x32_bf16(afr[kc], bfr, acc, 0, 0, 0);
            }
            const float bv = bias[nt * 16 + m];
            #pragma unroll
            for (int r = 0; r < 4; ++r)
                P1b[(size_t)(row0 + quad * 4 + r) * AA + nt * 16 + m] = f2b(acc[r] + bv);
        }
    }
}

// ---- K2: rowptr[f] = lower_bound(cp, f). Boundary scatter, cp sorted.
__global__ __launch_bounds__(256) void rowptr_kernel(
    const int* __restrict__ cp, int* __restrict__ rowptr)
{
    const int e = blockIdx.x * 256 + threadIdx.x;
    const int cur = cp[e];
    const int prev = (e == 0) ? -1 : cp[e - 1];
    for (int f = prev + 1; f <= cur; ++f) rowptr[f] = e;
    if (e == NE - 1)
        for (int f = cur + 1; f <= NF; ++f) rowptr[f] = NE;
}

// ---- K3: fused scoring + softmax + context -> ctx [NF][128] row-major.
// r8 shape + THIRD pipeline level for the index loads. r8's hidden stall:
// PRELOAD loaded fci then immediately shfl'd it -> full fci latency eaten
// per group before COMPUTE. Now: raw fci/corr loads run one group ahead of
// their shfl (the shfl happens in ISSUE, one COMPUTE later).
// Steady-state body: COMPUTE(g) ; ISSUE(g+2) from fci loaded last body ;
// LOADFCI(g+3). q/v stay depth-2 (A/B slots). State +2 VGPR vs r8 (~54),
// under the 64 cliff. No forced occupancy (r7 lesson).
__global__ __launch_bounds__(512) void scorectx_kernel(
    const unsigned short* __restrict__ embB,
    const unsigned short* __restrict__ P1b, const unsigned short* __restrict__ P2b,
    const float* __restrict__ uK, const float* __restrict__ corr,
    const int* __restrict__ rowptr, const int* __restrict__ fci,
    unsigned short* __restrict__ ctx)
{
    const int lane = threadIdx.x & 63;
    const int wave = threadIdx.x >> 6;       // 0..7
    const int f = blockIdx.x * 8 + wave;     // 2500 blocks * 8 waves = 20000 = NF

    const int c    = lane & 7;               // score: col-octet (8 dims each)
    const int slot = lane >> 3;              // score: edge-slot 0..7
    const int quar = lane >> 4;              // accum: edge-quarter 0..3
    const int hex  = lane & 15;              // accum: dim-slice index (8 dims)

    const float L2E   = 1.4426950408889634f;
    const float C2L2E = 2.8853900817779268f; // 2*log2(e)

    float m2l[8]; float suml2 = 0.f;
    {
        const float4 u0 = *(const float4*)&uK[c * 8];
        const float4 u1 = *(const float4*)&uK[c * 8 + 4];
        const float uu[8] = {u0.x,u0.y,u0.z,u0.w,u1.x,u1.y,u1.z,u1.w};
        #pragma unroll
        for (int k = 0; k < 8; ++k) { m2l[k] = -2.f * L2E * uu[k]; suml2 += L2E * uu[k]; }
    }

    const int start = rowptr[f], end = rowptr[f + 1];

    float p1sc[8];   // P1 row * 2log2e, dims c*8..c*8+7
    {
        const uint4 qv = *(const uint4*)&P1b[(size_t)f * AA + c * 8];
        p1sc[0] = __uint_as_float(qv.x << 16)          * C2L2E;
        p1sc[1] = __uint_as_float(qv.x & 0xFFFF0000u)  * C2L2E;
        p1sc[2] = __uint_as_float(qv.y << 16)          * C2L2E;
        p1sc[3] = __uint_as_float(qv.y & 0xFFFF0000u)  * C2L2E;
        p1sc[4] = __uint_as_float(qv.z << 16)          * C2L2E;
        p1sc[5] = __uint_as_float(qv.z & 0xFFFF0000u)  * C2L2E;
        p1sc[6] = __uint_as_float(qv.w << 16)          * C2L2E;
        p1sc[7] = __uint_as_float(qv.w & 0xFFFF0000u)  * C2L2E;
    }

    float acc[8] = {0.f,0.f,0.f,0.f,0.f,0.f,0.f,0.f};
    float den = 0.f;

    if (start < end) {
        // stage regs: idxN/crN = RAW next-to-issue fci/corr (no shfl yet);
        // q = P2 fragment of my slot's edge; v0/v1 = embB rows (quar, 4+quar)
        uint4 qA, v0A, v1A, qB, v0B, v1B;
        float crA, crB;
        int idxN = 0; float crN = 0.f;

        // raw index loads only - no dependent ops
        #define LOADFCI(e_)                                                        \
        {                                                                          \
            const int ee = (e_) + slot;                                            \
            const int ec = (ee < end) ? ee : (end - 1);                            \
            idxN = fci[ec];                                                        \
            crN  = corr[ec];                                                       \
        }

        // consume idxN/crN: validity select (no load dep), shfl, issue gathers
        #define ISSUE(e_, q_, v0_, v1_, cr_)                                       \
        {                                                                          \
            cr_ = (((e_) + slot) < end) ? crN : 0.f;                               \
            q_ = *(const uint4*)&P2b[(size_t)idxN * AA + c * 8];                   \
            const int i0 = __shfl(idxN, quar * 8);                                 \
            v0_ = *(const uint4*)&embB[(size_t)i0 * DD + hex * 8];                 \
            const int i1 = __shfl(idxN, (4 + quar) * 8);                           \
            v1_ = *(const uint4*)&embB[(size_t)i1 * DD + hex * 8];                 \
        }

        #define COMPUTE(q_, v0_, v1_, cr_)                                         \
        {                                                                          \
            float part = suml2;                                                    \
            {                                                                      \
                const float a0 = fmaf(__uint_as_float(q_.x << 16),         C2L2E, p1sc[0]); \
                const float a1 = fmaf(__uint_as_float(q_.x & 0xFFFF0000u), C2L2E, p1sc[1]); \
                const float a2 = fmaf(__uint_as_float(q_.y << 16),         C2L2E, p1sc[2]); \
                const float a3 = fmaf(__uint_as_float(q_.y & 0xFFFF0000u), C2L2E, p1sc[3]); \
                const float a4 = fmaf(__uint_as_float(q_.z << 16),         C2L2E, p1sc[4]); \
                const float a5 = fmaf(__uint_as_float(q_.z & 0xFFFF0000u), C2L2E, p1sc[5]); \
                const float a6 = fmaf(__uint_as_float(q_.w << 16),         C2L2E, p1sc[6]); \
                const float a7 = fmaf(__uint_as_float(q_.w & 0xFFFF0000u), C2L2E, p1sc[7]); \
                part = fmaf(__builtin_amdgcn_rcpf(exp2f(a0) + 1.f), m2l[0], part); \
                part = fmaf(__builtin_amdgcn_rcpf(exp2f(a1) + 1.f), m2l[1], part); \
                part = fmaf(__builtin_amdgcn_rcpf(exp2f(a2) + 1.f), m2l[2], part); \
                part = fmaf(__builtin_amdgcn_rcpf(exp2f(a3) + 1.f), m2l[3], part); \
                part = fmaf(__builtin_amdgcn_rcpf(exp2f(a4) + 1.f), m2l[4], part); \
                part = fmaf(__builtin_amdgcn_rcpf(exp2f(a5) + 1.f), m2l[5], part); \
                part = fmaf(__builtin_amdgcn_rcpf(exp2f(a6) + 1.f), m2l[6], part); \
                part = fmaf(__builtin_amdgcn_rcpf(exp2f(a7) + 1.f), m2l[7], part); \
            }                                                                      \
            part += __shfl_xor(part, 1);                                           \
            part += __shfl_xor(part, 2);                                           \
            part += __shfl_xor(part, 4);                                           \
            const float s = exp2f(part) * cr_;                                     \
            den += s;                                                              \
            const float s0 = __shfl(s, quar * 8);                                  \
            acc[0] = fmaf(s0, __uint_as_float(v0_.x << 16),         acc[0]);       \
            acc[1] = fmaf(s0, __uint_as_float(v0_.x & 0xFFFF0000u), acc[1]);       \
            acc[2] = fmaf(s0, __uint_as_float(v0_.y << 16),         acc[2]);       \
            acc[3] = fmaf(s0, __uint_as_float(v0_.y & 0xFFFF0000u), acc[3]);       \
            acc[4] = fmaf(s0, __uint_as_float(v0_.z << 16),         acc[4]);       \
            acc[5] = fmaf(s0, __uint_as_float(v0_.z & 0xFFFF0000u), acc[5]);       \
            acc[6] = fmaf(s0, __uint_as_float(v0_.w << 16),         acc[6]);       \
            acc[7] = fmaf(s0, __uint_as_float(v0_.w & 0xFFFF0000u), acc[7]);       \
            const float s1 = __shfl(s, (4 + quar) * 8);                            \
            acc[0] = fmaf(s1, __uint_as_float(v1_.x << 16),         acc[0]);       \
            acc[1] = fmaf(s1, __uint_as_float(v1_.x & 0xFFFF0000u), acc[1]);       \
            acc[2] = fmaf(s1, __uint_as_float(v1_.y << 16),         acc[2]);       \
            acc[3] = fmaf(s1, __uint_as_float(v1_.y & 0xFFFF0000u), acc[3]);       \
            acc[4] = fmaf(s1, __uint_as_float(v1_.z << 16),         acc[4]);       \
            acc[5] = fmaf(s1, __uint_as_float(v1_.z & 0xFFFF0000u), acc[5]);       \
            acc[6] = fmaf(s1, __uint_as_float(v1_.w << 16),         acc[6]);       \
            acc[7] = fmaf(s1, __uint_as_float(v1_.w & 0xFFFF0000u), acc[7]);       \
        }

        int e = start;
        // prologue: establish {A,B issued; idxN holds fci(g2)}
        LOADFCI(e);
        ISSUE(e, qA, v0A, v1A, crA);                 // unavoidable fci wait (once)
        if (e + 8 < end) {
            LOADFCI(e + 8);
            ISSUE(e + 8, qB, v0B, v1B, crB);         // second prologue wait (once)
            if (e + 16 < end) LOADFCI(e + 16);       // g2 in flight, no consumer yet
        }
        for (;;) {
            COMPUTE(qA, v0A, v1A, crA);              // group g   (slot A)
            if (e + 16 < end) {
                ISSUE(e + 16, qA, v0A, v1A, crA);    // group g+2 <- fci loaded 1 body ago
                if (e + 24 < end) LOADFCI(e + 24);   // group g+3 raw load
            }
            e += 8; if (e >= end) break;
            COMPUTE(qB, v0B, v1B, crB);              // group g+1 (slot B)
            if (e + 16 < end) {
                ISSUE(e + 16, qB, v0B, v1B, crB);
                if (e + 24 < end) LOADFCI(e + 24);
            }
            e += 8; if (e >= end) break;
        }
        #undef LOADFCI
        #undef ISSUE
        #undef COMPUTE
    }

    // acc is partial over this lane's edge-quarter; reduce across quarters.
    #pragma unroll
    for (int k = 0; k < 8; ++k) {
        acc[k] += __shfl_xor(acc[k], 16);
        acc[k] += __shfl_xor(acc[k], 32);
    }
    // den is per-slot; reduce across slot bits (3,4,5).
    den += __shfl_xor(den, 8);
    den += __shfl_xor(den, 16);
    den += __shfl_xor(den, 32);
    const float inv = (den != 0.f) ? 1.f / den : 0.f;

    if (lane < 16) {   // 16 lanes x uint4 = one full 256B line
        uint4 o;
        o.x = ((unsigned int)f2b(acc[1] * inv) << 16) | f2b(acc[0] * inv);
        o.y = ((unsigned int)f2b(acc[3] * inv) << 16) | f2b(acc[2] * inv);
        o.z = ((unsigned int)f2b(acc[5] * inv) << 16) | f2b(acc[4] * inv);
        o.w = ((unsigned int)f2b(acc[7] * inv) << 16) | f2b(acc[6] * inv);
        *(uint4*)&ctx[(size_t)f * DD + hex * 8] = o;
    }
}

// ---- K4: transpose ctx [NF][128] -> ctxT [128][NF] (bf16), full-line I/O both
// sides. Also zeroes `out` (folds the memset dispatch away; runs before outmm).
__global__ __launch_bounds__(256) void transpose_kernel(
    const unsigned short* __restrict__ ctx, unsigned short* __restrict__ ctxT,
    float* __restrict__ out)
{
    __shared__ unsigned int tile[64 * 33];   // [dpair][feat]: lo16=row 2d, hi16=row 2d+1
    const int t = threadIdx.x;
    const int gid = blockIdx.x * 256 + t;
    if (gid < (256 * DD) / 4) {              // 8192 float4 = 256x128 out zero-init
        f32x4 z = {0.f, 0.f, 0.f, 0.f};
        *(f32x4*)&out[gid * 4] = z;
    }
    const int f0 = blockIdx.x * 32;
    const int fl = t >> 3, db = t & 7;       // feature-local 0..31, dim-block (16 dims)
    const unsigned int* src = (const unsigned int*)&ctx[(size_t)(f0 + fl) * DD + db * 16];
    uint4 q0 = *(const uint4*)src;           // dims db*16+0..7 (u32 j: dims 2j,2j+1)
    uint4 q1 = *(const uint4*)(src + 4);     // dims db*16+8..15
    unsigned int w[8] = {q0.x, q0.y, q0.z, q0.w, q1.x, q1.y, q1.z, q1.w};
    #pragma unroll
    for (int j = 0; j < 8; ++j)
        tile[(db * 8 + j) * 33 + fl] = w[j];
    __syncthreads();

    const int r = t >> 1, side = t & 1;      // row 0..127, 16-feature half
    const int dpair = r >> 1, odd = r & 1;
    unsigned int o[8];
    #pragma unroll
    for (int i = 0; i < 8; ++i) {
        const int fo = side * 16 + i * 2;
        const unsigned int v0 = tile[dpair * 33 + fo];
        const unsigned int v1 = tile[dpair * 33 + fo + 1];
        o[i] = odd ? ((v1 & 0xFFFF0000u) | (v0 >> 16))
                   : ((v1 << 16) | (v0 & 0xFFFFu));
    }
    uint4 a = {o[0], o[1], o[2], o[3]}, b = {o[4], o[5], o[6], o[7]};
    *(uint4*)&ctxT[(size_t)r * NF + f0 + side * 16]     = a;
    *(uint4*)&ctxT[(size_t)r * NF + f0 + side * 16 + 8] = b;
}

// ---- K5: out[256,128] = values @ ctx via MFMA; values split hi/lo bf16 (exact).
// grid 500 (4 mgroups x 125 kchunks): full-chip occupancy (round-5 lesson).
__global__ __launch_bounds__(256) void outmm_kernel(
    const float* __restrict__ values, const unsigned short* __restrict__ ctxT,
    float* __restrict__ out)
{
    const int wave = threadIdx.x >> 6, lane = threadIdx.x & 63;
    const int m = lane & 15, quad = lane >> 4;
    const int mgroup = blockIdx.x & 3, kchunk = blockIdx.x >> 2;
    const int m0 = mgroup * 64 + wave * 16;
    const int k0 = kchunk * 160;

    f32x4 acc[8];
    #pragma unroll
    for (int nt = 0; nt < 8; ++nt) acc[nt] = (f32x4){0.f, 0.f, 0.f, 0.f};

    for (int ks = 0; ks < 5; ++ks) {
        const int kk = k0 + ks * 32 + quad * 8;
        const float* ap = &values[(size_t)(m0 + m) * NF + kk];
        float4 a0 = *(const float4*)ap;
        float4 a1 = *(const float4*)(ap + 4);
        float av[8] = {a0.x, a0.y, a0.z, a0.w, a1.x, a1.y, a1.z, a1.w};
        short8 ahi, alo;
        #pragma unroll
        for (int j = 0; j < 8; ++j) {
            unsigned short hv = f2b(av[j]);
            ahi[j] = (short)hv;
            alo[j] = (short)f2b(av[j] - b2f(hv));
        }
        #pragma unroll
        for (int nt = 0; nt < 8; ++nt) {
            short8 b = *(const short8*)&ctxT[(size_t)(nt * 16 + m) * NF + kk];
            acc[nt] = __builtin_amdgcn_mfma_f32_16x16x32_bf16(ahi, b, acc[nt], 0, 0, 0);
            acc[nt] = __builtin_amdgcn_mfma_f32_16x16x32_bf16(alo, b, acc[nt], 0, 0, 0);
        }
    }
    #pragma unroll
    for (int nt = 0; nt < 8; ++nt)
        #pragma unroll
        for (int r = 0; r < 4; ++r)
            atomicAdd(&out[(size_t)(m0 + quad * 4 + r) * DD + nt * 16 + m], acc[nt][r]);
}

extern "C" void kernel_launch(void* const* d_in, const int* in_sizes, int n_in,
                              void* d_out, int out_size, void* d_ws, size_t ws_size,
                              hipStream_t stream)
{
    const float* values  = (const float*)d_in[0];
    const float* featEmb = (const float*)d_in[1];
    const float* hidEmb  = (const float*)d_in[2];
    const float* wK      = (const float*)d_in[3];
    const float* wB      = (const float*)d_in[4];
    const float* uK      = (const float*)d_in[5];
    const float* corr    = (const float*)d_in[6];
    const int* cp        = (const int*)d_in[7];
    const int* fci       = (const int*)d_in[8];
    float* out = (float*)d_out;

    // ws layout (bytes, 16B-aligned):
    char* ws = (char*)d_ws;
    unsigned short* embB  = (unsigned short*)(ws);                   // 15,360,000
    unsigned short* P1b   = (unsigned short*)(ws + 15360000);        //  2,560,000
    unsigned short* P2b   = (unsigned short*)(ws + 17920000);        //  7,680,000
    unsigned short* ctx   = (unsigned short*)(ws + 25600000);        //  5,120,000
    unsigned short* ctxT  = (unsigned short*)(ws + 30720000);        //  5,120,000
    int*            rowptr= (int*)          (ws + 35840000);         //     80,004  (total ~35.9 MB)

    embproj_kernel  <<<938,  256, 0, stream>>>(featEmb, hidEmb, wK, wB, embB, P1b, P2b);
    rowptr_kernel   <<<2500, 256, 0, stream>>>(cp, rowptr);
    scorectx_kernel <<<2500, 512, 0, stream>>>(embB, P1b, P2b, uK, corr, rowptr, fci, ctx);
    transpose_kernel<<<625,  256, 0, stream>>>(ctx, ctxT, out);
    outmm_kernel    <<<500,  256, 0, stream>>>(values, ctxT, out);
}

// Round 11
// 180.594 us; speedup vs baseline: 1.0215x; 1.0215x over previous
//
#include <hip/hip_runtime.h>

#define NF   20000
#define NALL 60000
#define NE   640000
#define DD   128
#define AA   64

typedef __attribute__((ext_vector_type(8))) short short8;
typedef __attribute__((ext_vector_type(4))) float f32x4;

__device__ __forceinline__ unsigned short f2b(float x) {
    unsigned int u = __float_as_uint(x);
    return (unsigned short)((u + 0x7FFFu + ((u >> 16) & 1u)) >> 16);  // RNE
}
__device__ __forceinline__ float b2f(unsigned short v) {
    return __uint_as_float(((unsigned int)v) << 16);
}
__device__ __forceinline__ short8 pack8(float4 a, float4 b) {
    short8 r;
    r[0]=(short)f2b(a.x); r[1]=(short)f2b(a.y); r[2]=(short)f2b(a.z); r[3]=(short)f2b(a.w);
    r[4]=(short)f2b(b.x); r[5]=(short)f2b(b.y); r[6]=(short)f2b(b.z); r[7]=(short)f2b(b.w);
    return r;
}

// ---- K1: fused conv+proj + rowptr. Blocks [0,938): load fp32 embs, convert
// (write embB bf16), compute P1 = feat@W1+bias, P2 = [feat;hid]@W2 via MFMA.
// Blocks [938, 3438): rowptr[f] = lower_bound(cp, f) boundary scatter
// (independent work folded in to save a dispatch).
__global__ __launch_bounds__(256) void embproj_kernel(
    const float* __restrict__ featEmb, const float* __restrict__ hidEmb,
    const float* __restrict__ wK, const float* __restrict__ bias,
    unsigned short* __restrict__ embB,
    unsigned short* __restrict__ P1b, unsigned short* __restrict__ P2b,
    const int* __restrict__ cp, int* __restrict__ rowptr)
{
    if (blockIdx.x >= 938) {   // rowptr part
        const int e = (blockIdx.x - 938) * 256 + threadIdx.x;
        const int cur = cp[e];
        const int prev = (e == 0) ? -1 : cp[e - 1];
        for (int f = prev + 1; f <= cur; ++f) rowptr[f] = e;
        if (e == NE - 1)
            for (int f = cur + 1; f <= NF; ++f) rowptr[f] = NE;
        return;
    }
    const int wave = threadIdx.x >> 6, lane = threadIdx.x & 63;
    const int rt = blockIdx.x * 4 + wave;
    if (rt >= NALL / 16) return;
    const int row0 = rt * 16;
    const int m = lane & 15, quad = lane >> 4;

    const int row = row0 + m;   // NF % 16 == 0: no tile straddles the feat/hid boundary
    const float* src = (row < NF) ? featEmb + (size_t)row * DD
                                  : hidEmb + (size_t)(row - NF) * DD;
    short8 afr[4];
    #pragma unroll
    for (int kc = 0; kc < 4; ++kc) {
        float4 a0 = *(const float4*)&src[kc * 32 + quad * 8];
        float4 a1 = *(const float4*)&src[kc * 32 + quad * 8 + 4];
        afr[kc] = pack8(a0, a1);
        *(short8*)&embB[(size_t)row * DD + kc * 32 + quad * 8] = afr[kc];
    }

    const float* W2 = wK + DD * AA;   // rows 128..255 of w_kernel
    #pragma unroll
    for (int nt = 0; nt < 4; ++nt) {
        f32x4 acc = {0.f, 0.f, 0.f, 0.f};
        #pragma unroll
        for (int kc = 0; kc < 4; ++kc) {
            short8 bfr;
            #pragma unroll
            for (int j = 0; j < 8; ++j)
                bfr[j] = (short)f2b(W2[(kc * 32 + quad * 8 + j) * AA + nt * 16 + m]);
            acc = __builtin_amdgcn_mfma_f32_16x16x32_bf16(afr[kc], bfr, acc, 0, 0, 0);
        }
        #pragma unroll
        for (int r = 0; r < 4; ++r)   // C/D: col=lane&15, row=quad*4+r
            P2b[(size_t)(row0 + quad * 4 + r) * AA + nt * 16 + m] = f2b(acc[r]);
    }
    if (row0 < NF) {
        #pragma unroll
        for (int nt = 0; nt < 4; ++nt) {
            f32x4 acc = {0.f, 0.f, 0.f, 0.f};
            #pragma unroll
            for (int kc = 0; kc < 4; ++kc) {
                short8 bfr;
                #pragma unroll
                for (int j = 0; j < 8; ++j)
                    bfr[j] = (short)f2b(wK[(kc * 32 + quad * 8 + j) * AA + nt * 16 + m]);
                acc = __builtin_amdgcn_mfma_f32_16x16x32_bf16(afr[kc], bfr, acc, 0, 0, 0);
            }
            const float bv = bias[nt * 16 + m];
            #pragma unroll
            for (int r = 0; r < 4; ++r)
                P1b[(size_t)(row0 + quad * 4 + r) * AA + nt * 16 + m] = f2b(acc[r] + bv);
        }
    }
}

// ---- K3: fused scoring + softmax + context -> ctx [NF][128] row-major.
// EXACT r8 structure (proven 42.2 us; best of r4/r8/r10 scheduling variants).
// BW-bound conclusion: ~250 MB request traffic/dispatch at ~5.9 TB/s through
// L2/L3 - scheduling variants converge at 42-46 us, so keep the best one.
// Per 8-edge group: fci + corr + P2-uint4 + 2x embB-uint4 = 5 VMEM instrs.
// embB quarter-wave: ONE instr loads FOUR rows (lane l reads uint4 of row
// edge (l>>4), dim-slice (l&15)*8). acc[8]/lane over dim slice, partial per
// quarter; shfl_xor{16,32} reduce at end; den over slot bits {8,16,32}.
// lane<16 stores one full 256B line. No forced occupancy (r7 lesson).
__global__ __launch_bounds__(512) void scorectx_kernel(
    const unsigned short* __restrict__ embB,
    const unsigned short* __restrict__ P1b, const unsigned short* __restrict__ P2b,
    const float* __restrict__ uK, const float* __restrict__ corr,
    const int* __restrict__ rowptr, const int* __restrict__ fci,
    unsigned short* __restrict__ ctx)
{
    const int lane = threadIdx.x & 63;
    const int wave = threadIdx.x >> 6;       // 0..7
    const int f = blockIdx.x * 8 + wave;     // 2500 blocks * 8 waves = 20000 = NF

    const int c    = lane & 7;               // score: col-octet (8 dims each)
    const int slot = lane >> 3;              // score: edge-slot 0..7
    const int quar = lane >> 4;              // accum: edge-quarter 0..3
    const int hex  = lane & 15;              // accum: dim-slice index (8 dims)

    const float L2E   = 1.4426950408889634f;
    const float C2L2E = 2.8853900817779268f; // 2*log2(e)

    float m2l[8]; float suml2 = 0.f;
    {
        const float4 u0 = *(const float4*)&uK[c * 8];
        const float4 u1 = *(const float4*)&uK[c * 8 + 4];
        const float uu[8] = {u0.x,u0.y,u0.z,u0.w,u1.x,u1.y,u1.z,u1.w};
        #pragma unroll
        for (int k = 0; k < 8; ++k) { m2l[k] = -2.f * L2E * uu[k]; suml2 += L2E * uu[k]; }
    }

    const int start = rowptr[f], end = rowptr[f + 1];

    float p1sc[8];   // P1 row * 2log2e, dims c*8..c*8+7
    {
        const uint4 qv = *(const uint4*)&P1b[(size_t)f * AA + c * 8];
        p1sc[0] = __uint_as_float(qv.x << 16)          * C2L2E;
        p1sc[1] = __uint_as_float(qv.x & 0xFFFF0000u)  * C2L2E;
        p1sc[2] = __uint_as_float(qv.y << 16)          * C2L2E;
        p1sc[3] = __uint_as_float(qv.y & 0xFFFF0000u)  * C2L2E;
        p1sc[4] = __uint_as_float(qv.z << 16)          * C2L2E;
        p1sc[5] = __uint_as_float(qv.z & 0xFFFF0000u)  * C2L2E;
        p1sc[6] = __uint_as_float(qv.w << 16)          * C2L2E;
        p1sc[7] = __uint_as_float(qv.w & 0xFFFF0000u)  * C2L2E;
    }

    float acc[8] = {0.f,0.f,0.f,0.f,0.f,0.f,0.f,0.f};
    float den = 0.f;

    if (start < end) {
        // pipeline stages: q = P2 fragment (my slot's edge), v0/v1 = embB rows
        // (edges quar and 4+quar), cr = corr of my slot's edge (0 if invalid)
        uint4 qA, v0A, v1A, qB, v0B, v1B;
        float crA, crB;

        #define PRELOAD(e_, q_, v0_, v1_, cr_)                                     \
        {                                                                          \
            const int ee = (e_) + slot;                                            \
            const int ec = (ee < end) ? ee : (end - 1);                            \
            const int idx = fci[ec];                                               \
            const float crv = corr[ec];                                            \
            cr_ = (ee < end) ? crv : 0.f;                                          \
            q_ = *(const uint4*)&P2b[(size_t)idx * AA + c * 8];                    \
            const int i0 = __shfl(idx, quar * 8);                                  \
            v0_ = *(const uint4*)&embB[(size_t)i0 * DD + hex * 8];                 \
            const int i1 = __shfl(idx, (4 + quar) * 8);                            \
            v1_ = *(const uint4*)&embB[(size_t)i1 * DD + hex * 8];                 \
        }

        #define COMPUTE(q_, v0_, v1_, cr_)                                         \
        {                                                                          \
            float part = suml2;                                                    \
            {                                                                      \
                const float a0 = fmaf(__uint_as_float(q_.x << 16),         C2L2E, p1sc[0]); \
                const float a1 = fmaf(__uint_as_float(q_.x & 0xFFFF0000u), C2L2E, p1sc[1]); \
                const float a2 = fmaf(__uint_as_float(q_.y << 16),         C2L2E, p1sc[2]); \
                const float a3 = fmaf(__uint_as_float(q_.y & 0xFFFF0000u), C2L2E, p1sc[3]); \
                const float a4 = fmaf(__uint_as_float(q_.z << 16),         C2L2E, p1sc[4]); \
                const float a5 = fmaf(__uint_as_float(q_.z & 0xFFFF0000u), C2L2E, p1sc[5]); \
                const float a6 = fmaf(__uint_as_float(q_.w << 16),         C2L2E, p1sc[6]); \
                const float a7 = fmaf(__uint_as_float(q_.w & 0xFFFF0000u), C2L2E, p1sc[7]); \
                part = fmaf(__builtin_amdgcn_rcpf(exp2f(a0) + 1.f), m2l[0], part); \
                part = fmaf(__builtin_amdgcn_rcpf(exp2f(a1) + 1.f), m2l[1], part); \
                part = fmaf(__builtin_amdgcn_rcpf(exp2f(a2) + 1.f), m2l[2], part); \
                part = fmaf(__builtin_amdgcn_rcpf(exp2f(a3) + 1.f), m2l[3], part); \
                part = fmaf(__builtin_amdgcn_rcpf(exp2f(a4) + 1.f), m2l[4], part); \
                part = fmaf(__builtin_amdgcn_rcpf(exp2f(a5) + 1.f), m2l[5], part); \
                part = fmaf(__builtin_amdgcn_rcpf(exp2f(a6) + 1.f), m2l[6], part); \
                part = fmaf(__builtin_amdgcn_rcpf(exp2f(a7) + 1.f), m2l[7], part); \
            }                                                                      \
            part += __shfl_xor(part, 1);                                           \
            part += __shfl_xor(part, 2);                                           \
            part += __shfl_xor(part, 4);                                           \
            const float s = exp2f(part) * cr_;                                     \
            den += s;                                                              \
            const float s0 = __shfl(s, quar * 8);                                  \
            acc[0] = fmaf(s0, __uint_as_float(v0_.x << 16),         acc[0]);       \
            acc[1] = fmaf(s0, __uint_as_float(v0_.x & 0xFFFF0000u), acc[1]);       \
            acc[2] = fmaf(s0, __uint_as_float(v0_.y << 16),         acc[2]);       \
            acc[3] = fmaf(s0, __uint_as_float(v0_.y & 0xFFFF0000u), acc[3]);       \
            acc[4] = fmaf(s0, __uint_as_float(v0_.z << 16),         acc[4]);       \
            acc[5] = fmaf(s0, __uint_as_float(v0_.z & 0xFFFF0000u), acc[5]);       \
            acc[6] = fmaf(s0, __uint_as_float(v0_.w << 16),         acc[6]);       \
            acc[7] = fmaf(s0, __uint_as_float(v0_.w & 0xFFFF0000u), acc[7]);       \
            const float s1 = __shfl(s, (4 + quar) * 8);                            \
            acc[0] = fmaf(s1, __uint_as_float(v1_.x << 16),         acc[0]);       \
            acc[1] = fmaf(s1, __uint_as_float(v1_.x & 0xFFFF0000u), acc[1]);       \
            acc[2] = fmaf(s1, __uint_as_float(v1_.y << 16),         acc[2]);       \
            acc[3] = fmaf(s1, __uint_as_float(v1_.y & 0xFFFF0000u), acc[3]);       \
            acc[4] = fmaf(s1, __uint_as_float(v1_.z << 16),         acc[4]);       \
            acc[5] = fmaf(s1, __uint_as_float(v1_.z & 0xFFFF0000u), acc[5]);       \
            acc[6] = fmaf(s1, __uint_as_float(v1_.w << 16),         acc[6]);       \
            acc[7] = fmaf(s1, __uint_as_float(v1_.w & 0xFFFF0000u), acc[7]);       \
        }

        int e = start;
        PRELOAD(e, qA, v0A, v1A, crA);
        e += 8;
        for (; e < end; e += 16) {
            PRELOAD(e, qB, v0B, v1B, crB);
            COMPUTE(qA, v0A, v1A, crA);
            if (e + 8 < end) {
                PRELOAD(e + 8, qA, v0A, v1A, crA);
                COMPUTE(qB, v0B, v1B, crB);
            } else {
                COMPUTE(qB, v0B, v1B, crB);
                goto done;
            }
        }
        COMPUTE(qA, v0A, v1A, crA);
        done: ;
        #undef PRELOAD
        #undef COMPUTE
    }

    // acc is partial over this lane's edge-quarter; reduce across quarters.
    #pragma unroll
    for (int k = 0; k < 8; ++k) {
        acc[k] += __shfl_xor(acc[k], 16);
        acc[k] += __shfl_xor(acc[k], 32);
    }
    // den is per-slot; reduce across slot bits (3,4,5).
    den += __shfl_xor(den, 8);
    den += __shfl_xor(den, 16);
    den += __shfl_xor(den, 32);
    const float inv = (den != 0.f) ? 1.f / den : 0.f;

    if (lane < 16) {   // 16 lanes x uint4 = one full 256B line
        uint4 o;
        o.x = ((unsigned int)f2b(acc[1] * inv) << 16) | f2b(acc[0] * inv);
        o.y = ((unsigned int)f2b(acc[3] * inv) << 16) | f2b(acc[2] * inv);
        o.z = ((unsigned int)f2b(acc[5] * inv) << 16) | f2b(acc[4] * inv);
        o.w = ((unsigned int)f2b(acc[7] * inv) << 16) | f2b(acc[6] * inv);
        *(uint4*)&ctx[(size_t)f * DD + hex * 8] = o;
    }
}

// ---- K4: transpose ctx [NF][128] -> ctxT [128][NF] (bf16), full-line I/O both
// sides. Also zeroes `out` (folds the memset dispatch away; runs before outmm).
__global__ __launch_bounds__(256) void transpose_kernel(
    const unsigned short* __restrict__ ctx, unsigned short* __restrict__ ctxT,
    float* __restrict__ out)
{
    __shared__ unsigned int tile[64 * 33];   // [dpair][feat]: lo16=row 2d, hi16=row 2d+1
    const int t = threadIdx.x;
    const int gid = blockIdx.x * 256 + t;
    if (gid < (256 * DD) / 4) {              // 8192 float4 = 256x128 out zero-init
        f32x4 z = {0.f, 0.f, 0.f, 0.f};
        *(f32x4*)&out[gid * 4] = z;
    }
    const int f0 = blockIdx.x * 32;
    const int fl = t >> 3, db = t & 7;       // feature-local 0..31, dim-block (16 dims)
    const unsigned int* src = (const unsigned int*)&ctx[(size_t)(f0 + fl) * DD + db * 16];
    uint4 q0 = *(const uint4*)src;           // dims db*16+0..7 (u32 j: dims 2j,2j+1)
    uint4 q1 = *(const uint4*)(src + 4);     // dims db*16+8..15
    unsigned int w[8] = {q0.x, q0.y, q0.z, q0.w, q1.x, q1.y, q1.z, q1.w};
    #pragma unroll
    for (int j = 0; j < 8; ++j)
        tile[(db * 8 + j) * 33 + fl] = w[j];
    __syncthreads();

    const int r = t >> 1, side = t & 1;      // row 0..127, 16-feature half
    const int dpair = r >> 1, odd = r & 1;
    unsigned int o[8];
    #pragma unroll
    for (int i = 0; i < 8; ++i) {
        const int fo = side * 16 + i * 2;
        const unsigned int v0 = tile[dpair * 33 + fo];
        const unsigned int v1 = tile[dpair * 33 + fo + 1];
        o[i] = odd ? ((v1 & 0xFFFF0000u) | (v0 >> 16))
                   : ((v1 << 16) | (v0 & 0xFFFFu));
    }
    uint4 a = {o[0], o[1], o[2], o[3]}, b = {o[4], o[5], o[6], o[7]};
    *(uint4*)&ctxT[(size_t)r * NF + f0 + side * 16]     = a;
    *(uint4*)&ctxT[(size_t)r * NF + f0 + side * 16 + 8] = b;
}

// ---- K5: out[256,128] = values @ ctx via MFMA; values split hi/lo bf16 (exact).
// grid 500 (4 mgroups x 125 kchunks): full-chip occupancy (round-5 lesson).
__global__ __launch_bounds__(256) void outmm_kernel(
    const float* __restrict__ values, const unsigned short* __restrict__ ctxT,
    float* __restrict__ out)
{
    const int wave = threadIdx.x >> 6, lane = threadIdx.x & 63;
    const int m = lane & 15, quad = lane >> 4;
    const int mgroup = blockIdx.x & 3, kchunk = blockIdx.x >> 2;
    const int m0 = mgroup * 64 + wave * 16;
    const int k0 = kchunk * 160;

    f32x4 acc[8];
    #pragma unroll
    for (int nt = 0; nt < 8; ++nt) acc[nt] = (f32x4){0.f, 0.f, 0.f, 0.f};

    for (int ks = 0; ks < 5; ++ks) {
        const int kk = k0 + ks * 32 + quad * 8;
        const float* ap = &values[(size_t)(m0 + m) * NF + kk];
        float4 a0 = *(const float4*)ap;
        float4 a1 = *(const float4*)(ap + 4);
        float av[8] = {a0.x, a0.y, a0.z, a0.w, a1.x, a1.y, a1.z, a1.w};
        short8 ahi, alo;
        #pragma unroll
        for (int j = 0; j < 8; ++j) {
            unsigned short hv = f2b(av[j]);
            ahi[j] = (short)hv;
            alo[j] = (short)f2b(av[j] - b2f(hv));
        }
        #pragma unroll
        for (int nt = 0; nt < 8; ++nt) {
            short8 b = *(const short8*)&ctxT[(size_t)(nt * 16 + m) * NF + kk];
            acc[nt] = __builtin_amdgcn_mfma_f32_16x16x32_bf16(ahi, b, acc[nt], 0, 0, 0);
            acc[nt] = __builtin_amdgcn_mfma_f32_16x16x32_bf16(alo, b, acc[nt], 0, 0, 0);
        }
    }
    #pragma unroll
    for (int nt = 0; nt < 8; ++nt)
        #pragma unroll
        for (int r = 0; r < 4; ++r)
            atomicAdd(&out[(size_t)(m0 + quad * 4 + r) * DD + nt * 16 + m], acc[nt][r]);
}

extern "C" void kernel_launch(void* const* d_in, const int* in_sizes, int n_in,
                              void* d_out, int out_size, void* d_ws, size_t ws_size,
                              hipStream_t stream)
{
    const float* values  = (const float*)d_in[0];
    const float* featEmb = (const float*)d_in[1];
    const float* hidEmb  = (const float*)d_in[2];
    const float* wK      = (const float*)d_in[3];
    const float* wB      = (const float*)d_in[4];
    const float* uK      = (const float*)d_in[5];
    const float* corr    = (const float*)d_in[6];
    const int* cp        = (const int*)d_in[7];
    const int* fci       = (const int*)d_in[8];
    float* out = (float*)d_out;

    // ws layout (bytes, 16B-aligned):
    char* ws = (char*)d_ws;
    unsigned short* embB  = (unsigned short*)(ws);                   // 15,360,000
    unsigned short* P1b   = (unsigned short*)(ws + 15360000);        //  2,560,000
    unsigned short* P2b   = (unsigned short*)(ws + 17920000);        //  7,680,000
    unsigned short* ctx   = (unsigned short*)(ws + 25600000);        //  5,120,000
    unsigned short* ctxT  = (unsigned short*)(ws + 30720000);        //  5,120,000
    int*            rowptr= (int*)          (ws + 35840000);         //     80,004  (total ~35.9 MB)

    embproj_kernel  <<<3438, 256, 0, stream>>>(featEmb, hidEmb, wK, wB, embB, P1b, P2b,
                                               cp, rowptr);
    scorectx_kernel <<<2500, 512, 0, stream>>>(embB, P1b, P2b, uK, corr, rowptr, fci, ctx);
    transpose_kernel<<<625,  256, 0, stream>>>(ctx, ctxT, out);
    outmm_kernel    <<<500,  256, 0, stream>>>(values, ctxT, out);
}